// Round 10
// baseline (409.142 us; speedup 1.0000x reference)
//
#include <hip/hip_runtime.h>
#include <cstdint>

#define N_NODES 50000
#define N_EDGES 800000
#define EPCAP 64

typedef _Float16 half8 __attribute__((ext_vector_type(8)));
typedef float f32x4 __attribute__((ext_vector_type(4)));

// ---------------- f16 helpers ----------------

__device__ inline unsigned pack_half2(float lo, float hi) {
    union { _Float16 h[2]; unsigned u; } cv;
    cv.h[0] = (_Float16)lo; cv.h[1] = (_Float16)hi;
    return cv.u;
}
__device__ inline float h_lo(unsigned u) {
    union { unsigned u; _Float16 h[2]; } cv; cv.u = u; return (float)cv.h[0];
}
__device__ inline float h_hi(unsigned u) {
    union { unsigned u; _Float16 h[2]; } cv; cv.u = u; return (float)cv.h[1];
}

// ---------------- scatter (blocks 0..3124) + W transpose/convert (3125..3127) ----------
// ep[row*64 + slot] = (f16val << 16) | col ; qsum[col] += f16val (for colsum(f3) identity)

__global__ __launch_bounds__(256) void scatter_wprep_kernel(const int* __restrict__ rows,
                                                            const int* __restrict__ cols,
                                                            const float* __restrict__ vals,
                                                            int* __restrict__ cnt,
                                                            unsigned* __restrict__ ep,
                                                            float* __restrict__ qsum,
                                                            const float* __restrict__ w3,
                                                            const float* __restrict__ w2,
                                                            const float* __restrict__ w1,
                                                            _Float16* __restrict__ Wt) {
    int bx = blockIdx.x;
    if (bx >= 3125) {
        int b = bx - 3125;
        const float* W = (b == 0) ? w3 : (b == 1) ? w2 : w1;
        _Float16* O = Wt + (size_t)b * 16384;
        for (int i = threadIdx.x; i < 16384; i += 256) {
            int j = i >> 7, d = i & 127;
            O[j * 128 + d] = (_Float16)W[d * 128 + j];
        }
        return;
    }
    int e = bx * 256 + threadIdx.x;  // 3125*256 == 800000 exactly
    int r = rows[e];
    int c = cols[e];
    int p = atomicAdd(&cnt[r], 1);
    union { _Float16 h; unsigned short s; } cv; cv.h = (_Float16)vals[e];
    if (p < EPCAP)
        __builtin_nontemporal_store(((unsigned)cv.s << 16) | (unsigned)c,
                                    &ep[(size_t)r * EPCAP + p]);
    atomicAdd(&qsum[c], (float)cv.h);
}

// ---------------- fused 3-branch MFMA GEMM (round-7 known-good) ----------------
// T1 chunked layout: dword (row*192 + b*64 + j) = branch b, dims (j, j+64)

__global__ __launch_bounds__(256) void gemm_mfma3_kernel(const float* __restrict__ F,
                                                         const _Float16* __restrict__ Wt,
                                                         unsigned* __restrict__ T1, int nrows) {
    __shared__ _Float16 Fs[64 * 128];    // 16 KiB, XOR-swizzled rows
    __shared__ _Float16 Ws[128 * 128];   // 32 KiB, [j][k] XOR-swizzled
    int tid = threadIdx.x;
    int lane = tid & 63, wv = tid >> 6;
    int c = lane & 15, g = lane >> 4;
    int rowbase = blockIdx.x * 64;

    for (int i = tid; i < 4096; i += 256) {
        int r = i >> 6;
        int row = rowbase + r; if (row >= nrows) row = nrows - 1;
        float2 fv = ((const float2*)F)[(size_t)row * 64 + (i & 63)];
        *(unsigned*)((char*)Fs + ((i * 4) ^ ((r & 15) << 4))) = pack_half2(fv.x, fv.y);
    }
    __syncthreads();

    half8 afr[4];
    #pragma unroll
    for (int ks = 0; ks < 4; ++ks) {
        int off = (((wv * 16 + c) * 128 + ks * 32 + g * 8) * 2) ^ (c << 4);
        afr[ks] = *(const half8*)((const char*)Fs + off);
    }

    for (int b = 0; b < 3; ++b) {
        const unsigned* WtU = (const unsigned*)(Wt + (size_t)b * 16384);
        for (int i = tid; i < 8192; i += 256) {
            int j = i >> 6;
            *(unsigned*)((char*)Ws + ((i * 4) ^ ((j & 15) << 4))) = WtU[i];
        }
        __syncthreads();

        f32x4 zero = {0.f, 0.f, 0.f, 0.f};
        f32x4 acc[8];
        #pragma unroll
        for (int t = 0; t < 8; ++t) acc[t] = zero;

        #pragma unroll
        for (int ks = 0; ks < 4; ++ks) {
            #pragma unroll
            for (int t = 0; t < 8; ++t) {
                int j = t * 16 + c;
                int off = ((j * 128 + ks * 32 + g * 8) * 2) ^ ((j & 15) << 4);
                half8 bfr = *(const half8*)((const char*)Ws + off);
                acc[t] = __builtin_amdgcn_mfma_f32_16x16x32_f16(afr[ks], bfr, acc[t], 0, 0, 0);
            }
        }

        #pragma unroll
        for (int t = 0; t < 4; ++t) {
            int j = t * 16 + c;
            #pragma unroll
            for (int r = 0; r < 4; ++r) {
                int row = rowbase + wv * 16 + g * 4 + r;
                if (row < N_NODES)
                    T1[(size_t)row * 192 + b * 64 + j] =
                        pack_half2(tanhf(acc[t][r]), tanhf(acc[t + 4][r]));
            }
        }
        __syncthreads();
    }
}

// ---------------- S1: NCHUNK=3 (round-7 exact) ----------------
// T1 -> [u3|v2](T2) + f1h (f16) + csum slot 0

__global__ __launch_bounds__(512) void spmm1_kernel(const int* __restrict__ cnts,
                                                    const unsigned* __restrict__ ep,
                                                    const unsigned* __restrict__ x,
                                                    unsigned* __restrict__ ob0,
                                                    unsigned* __restrict__ obf,
                                                    float* __restrict__ csum) {
    __shared__ float cs[128];
    int tid = threadIdx.x;
    if (tid < 128) cs[tid] = 0.f;
    __syncthreads();

    int row = blockIdx.x * 8 + (tid >> 6);
    int lane = tid & 63;
    int n = __builtin_amdgcn_readfirstlane(cnts[row]);
    n = n < EPCAP ? n : EPCAP;
    const unsigned* e0 = ep + (size_t)row * EPCAP;

    float ax[3] = {0.f, 0.f, 0.f}, ay[3] = {0.f, 0.f, 0.f};
    const unsigned* xl = x + lane;
    constexpr int U = 8;
    int i = 0;
    for (; i + U <= n; i += U) {
        unsigned p[U];
        #pragma unroll
        for (int u = 0; u < U; ++u) p[u] = e0[i + u];
        unsigned gx[U][3];
        #pragma unroll
        for (int u = 0; u < U; ++u) {
            unsigned b = (p[u] & 0xFFFFu) * 192u;
            #pragma unroll
            for (int cc = 0; cc < 3; ++cc) gx[u][cc] = xl[b + cc * 64];
        }
        #pragma unroll
        for (int u = 0; u < U; ++u) {
            union { unsigned short s; _Float16 h; } cu; cu.s = (unsigned short)(p[u] >> 16);
            float v = (float)cu.h;
            #pragma unroll
            for (int cc = 0; cc < 3; ++cc) {
                ax[cc] += v * h_lo(gx[u][cc]);
                ay[cc] += v * h_hi(gx[u][cc]);
            }
        }
    }
    for (; i < n; ++i) {
        unsigned p = e0[i];
        unsigned b = (p & 0xFFFFu) * 192u;
        union { unsigned short s; _Float16 h; } cu; cu.s = (unsigned short)(p >> 16);
        float v = (float)cu.h;
        #pragma unroll
        for (int cc = 0; cc < 3; ++cc) {
            unsigned gg = xl[b + cc * 64];
            ax[cc] += v * h_lo(gg);
            ay[cc] += v * h_hi(gg);
        }
    }

    // chunks 0,1 -> T2 [u3|v2]
    ob0[(size_t)row * 128 + 0 * 64 + lane] = pack_half2(ax[0], ay[0]);
    ob0[(size_t)row * 128 + 1 * 64 + lane] = pack_half2(ax[1], ay[1]);
    // final chunk -> f1h + csum slot 0
    obf[(size_t)row * 64 + lane] = pack_half2(ax[2], ay[2]);
    atomicAdd(&cs[2 * lane + 0], ax[2]);
    atomicAdd(&cs[2 * lane + 1], ay[2]);
    __syncthreads();
    if (tid < 128) atomicAdd(&csum[(blockIdx.x & 7) * 384 + tid], cs[tid]);
}

// ---------------- S2: NCHUNK=2, + csum slot2 via q-identity ----------------
// T2 -> [w3](T3) + f2h (csum slot 1); csum slot2 += q[row] * T3[row]

__global__ __launch_bounds__(512) void spmm2_kernel(const int* __restrict__ cnts,
                                                    const unsigned* __restrict__ ep,
                                                    const unsigned* __restrict__ x,
                                                    unsigned* __restrict__ T3,
                                                    unsigned* __restrict__ f2h,
                                                    const float* __restrict__ qsum,
                                                    float* __restrict__ csum) {
    __shared__ float cs[256];
    int tid = threadIdx.x;
    if (tid < 256) cs[tid] = 0.f;
    __syncthreads();

    int row = blockIdx.x * 8 + (tid >> 6);
    int lane = tid & 63;
    int n = __builtin_amdgcn_readfirstlane(cnts[row]);
    n = n < EPCAP ? n : EPCAP;
    const unsigned* e0 = ep + (size_t)row * EPCAP;

    float ax0 = 0.f, ay0 = 0.f, ax1 = 0.f, ay1 = 0.f;
    const unsigned* xl = x + lane;
    constexpr int U = 8;
    int i = 0;
    for (; i + U <= n; i += U) {
        unsigned p[U];
        #pragma unroll
        for (int u = 0; u < U; ++u) p[u] = e0[i + u];
        unsigned g0[U], g1[U];
        #pragma unroll
        for (int u = 0; u < U; ++u) {
            unsigned b = (p[u] & 0xFFFFu) * 128u;
            g0[u] = xl[b];
            g1[u] = xl[b + 64];
        }
        #pragma unroll
        for (int u = 0; u < U; ++u) {
            union { unsigned short s; _Float16 h; } cu; cu.s = (unsigned short)(p[u] >> 16);
            float v = (float)cu.h;
            ax0 += v * h_lo(g0[u]); ay0 += v * h_hi(g0[u]);
            ax1 += v * h_lo(g1[u]); ay1 += v * h_hi(g1[u]);
        }
    }
    for (; i < n; ++i) {
        unsigned p = e0[i];
        unsigned b = (p & 0xFFFFu) * 128u;
        union { unsigned short s; _Float16 h; } cu; cu.s = (unsigned short)(p >> 16);
        float v = (float)cu.h;
        unsigned g0 = xl[b], g1 = xl[b + 64];
        ax0 += v * h_lo(g0); ay0 += v * h_hi(g0);
        ax1 += v * h_lo(g1); ay1 += v * h_hi(g1);
    }

    // chunk0 -> T3; csum slot2 += q[row]*T3row (colsum(f3) = q^T T3)
    T3[(size_t)row * 64 + lane] = pack_half2(ax0, ay0);
    float qr = qsum[row];
    atomicAdd(&cs[128 + 2 * lane + 0], qr * ax0);
    atomicAdd(&cs[128 + 2 * lane + 1], qr * ay0);
    // chunk1 (f2) -> f2h + csum slot1
    f2h[(size_t)row * 64 + lane] = pack_half2(ax1, ay1);
    atomicAdd(&cs[2 * lane + 0], ax1);
    atomicAdd(&cs[2 * lane + 1], ay1);
    __syncthreads();
    // cs[0..127] -> slot1 (base 128), cs[128..255] -> slot2 (base 256)
    if (tid < 256) atomicAdd(&csum[(blockIdx.x & 7) * 384 + 128 + tid], cs[tid]);
}

// ---------------- S3 + combine: gather f3 in regs, FC+softmax head, write d_out ----------
// All csum slots complete after S2. Each block redundantly computes wgt (cheap, L2-hot).

__global__ __launch_bounds__(512) void spmm3_combine_kernel(const int* __restrict__ cnts,
                                                            const unsigned* __restrict__ ep,
                                                            const unsigned* __restrict__ x,
                                                            const unsigned* __restrict__ f1h,
                                                            const unsigned* __restrict__ f2h,
                                                            const float* __restrict__ csum,
                                                            const float* __restrict__ b1,
                                                            const float* __restrict__ b2,
                                                            const float* __restrict__ b3,
                                                            const float* __restrict__ fc1w,
                                                            const float* __restrict__ fc1b,
                                                            const float* __restrict__ fc2w,
                                                            const float* __restrict__ fc2b,
                                                            float* __restrict__ out) {
    __shared__ float m[3][128];
    __shared__ float rr[3][32];
    __shared__ float wgtS[3][128];
    int tid = threadIdx.x;

    // ---- FC + softmax head (round-7 combine head, slot remap for dim-split csum) ----
    if (tid < 128) {
        const float inv = 1.0f / (float)N_NODES;
        int slot = (tid < 64) ? (2 * tid) : (2 * (tid - 64) + 1);
        #pragma unroll
        for (int k = 0; k < 3; ++k) {
            float s = 0.f;
            #pragma unroll
            for (int rep = 0; rep < 8; ++rep) s += csum[rep * 384 + k * 128 + slot];
            const float* bk = (k == 0) ? b1 : (k == 1) ? b2 : b3;
            m[k][tid] = s * inv + bk[tid];
        }
    }
    __syncthreads();
    if (tid < 96) {
        int k = tid >> 5, j = tid & 31;
        float acc = fc1b[j];
        for (int d = 0; d < 128; ++d) acc += m[k][d] * fc1w[d * 32 + j];
        rr[k][j] = fmaxf(acc, 0.f);
    }
    __syncthreads();
    if (tid < 128) {
        float a[3];
        #pragma unroll
        for (int k = 0; k < 3; ++k) {
            float acc = fc2b[tid];
            for (int j = 0; j < 32; ++j) acc += rr[k][j] * fc2w[j * 128 + tid];
            a[k] = acc;
        }
        float mx = fmaxf(a[0], fmaxf(a[1], a[2]));
        float e0 = expf(a[0] - mx), e1 = expf(a[1] - mx), e2 = expf(a[2] - mx);
        float s = e0 + e1 + e2;
        wgtS[0][tid] = e0 / s;
        wgtS[1][tid] = e1 / s;
        wgtS[2][tid] = e2 / s;
    }
    __syncthreads();

    int lane = tid & 63;
    int row = blockIdx.x * 8 + (tid >> 6);

    // per-thread combine constants: dims (lane, lane+64)
    float g0lo = wgtS[0][lane], g0hi = wgtS[0][lane + 64];
    float g1lo = wgtS[1][lane], g1hi = wgtS[1][lane + 64];
    float g2lo = wgtS[2][lane], g2hi = wgtS[2][lane + 64];
    float b1lo = b1[lane], b1hi = b1[lane + 64];
    float b2lo = b2[lane], b2hi = b2[lane + 64];
    float b3lo = b3[lane], b3hi = b3[lane + 64];

    // ---- gather f3 row (NCHUNK=1) ----
    int n = __builtin_amdgcn_readfirstlane(cnts[row]);
    n = n < EPCAP ? n : EPCAP;
    const unsigned* e0 = ep + (size_t)row * EPCAP;
    const unsigned* xl = x + lane;

    float fx = 0.f, fy = 0.f;
    constexpr int U = 8;
    int i = 0;
    for (; i + U <= n; i += U) {
        unsigned p[U];
        #pragma unroll
        for (int u = 0; u < U; ++u) p[u] = e0[i + u];
        unsigned gg[U];
        #pragma unroll
        for (int u = 0; u < U; ++u) gg[u] = xl[(p[u] & 0xFFFFu) * 64u];
        #pragma unroll
        for (int u = 0; u < U; ++u) {
            union { unsigned short s; _Float16 h; } cu; cu.s = (unsigned short)(p[u] >> 16);
            float v = (float)cu.h;
            fx += v * h_lo(gg[u]);
            fy += v * h_hi(gg[u]);
        }
    }
    for (; i < n; ++i) {
        unsigned p = e0[i];
        unsigned gg = xl[(p & 0xFFFFu) * 64u];
        union { unsigned short s; _Float16 h; } cu; cu.s = (unsigned short)(p >> 16);
        float v = (float)cu.h;
        fx += v * h_lo(gg);
        fy += v * h_hi(gg);
    }

    // ---- combine + write ----
    unsigned u1 = f1h[(size_t)row * 64 + lane];
    unsigned u2 = f2h[(size_t)row * 64 + lane];
    out[(size_t)row * 128 + lane] =
        (h_lo(u1) + b1lo) * g0lo + (h_lo(u2) + b2lo) * g1lo + (fx + b3lo) * g2lo;
    out[(size_t)row * 128 + 64 + lane] =
        (h_hi(u1) + b1hi) * g0hi + (h_hi(u2) + b2hi) * g1hi + (fy + b3hi) * g2hi;
}

// ---------------- launch ----------------

extern "C" void kernel_launch(void* const* d_in, const int* in_sizes, int n_in,
                              void* d_out, int out_size, void* d_ws, size_t ws_size,
                              hipStream_t stream) {
    const float* F    = (const float*)d_in[0];
    const int*   erow = (const int*)d_in[1];
    const int*   ecol = (const int*)d_in[2];
    const float* eval_ = (const float*)d_in[3];
    const float* w1 = (const float*)d_in[4];  const float* b1 = (const float*)d_in[5];
    const float* w2 = (const float*)d_in[6];  const float* b2 = (const float*)d_in[7];
    const float* w3 = (const float*)d_in[8];  const float* b3 = (const float*)d_in[9];
    const float* fc1w = (const float*)d_in[10]; const float* fc1b = (const float*)d_in[11];
    const float* fc2w = (const float*)d_in[12]; const float* fc2b = (const float*)d_in[13];
    float* out = (float*)d_out;

    char* ws = (char*)d_ws;
    size_t off = 0;
    auto alloc = [&](size_t bytes) -> void* {
        off = (off + 255) & ~(size_t)255;
        void* p = ws + off;
        off += bytes;
        return p;
    };
    unsigned* T1   = (unsigned*)alloc((size_t)N_NODES * 192 * 4);       // 38.4 MB [h3|h2|h1]
    unsigned* T2   = (unsigned*)alloc((size_t)N_NODES * 128 * 4);       // 25.6 MB [u3|v2]
    unsigned* T3   = (unsigned*)alloc((size_t)N_NODES * 64 * 4);        // 12.8 MB [w3]
    unsigned* f1h  = (unsigned*)alloc((size_t)N_NODES * 64 * 4);        // 12.8 MB f1 (f16)
    unsigned* ep   = (unsigned*)alloc((size_t)N_NODES * EPCAP * 4);     // 12.8 MB edge buckets
    int*   counts  = (int*)alloc((size_t)N_NODES * sizeof(int));        // zeroed region start
    float* csum    = (float*)alloc(8 * 3 * 128 * sizeof(float));
    float* qsum    = (float*)alloc((size_t)N_NODES * sizeof(float));    // zeroed region end
    _Float16* Wt   = (_Float16*)alloc(3 * 16384 * sizeof(_Float16));    // 96 KB
    unsigned* f2h  = T1;                               // alias: T1 dead after S1
    unsigned* f3s  = T1 + (size_t)N_NODES * 64;        // (unused spare)
    (void)f3s;

    // one memset covers counts + csum + qsum (allocated adjacently)
    size_t zlen = (size_t)((char*)qsum + (size_t)N_NODES * sizeof(float) - (char*)counts);
    hipMemsetAsync(counts, 0, zlen, stream);

    scatter_wprep_kernel<<<3125 + 3, 256, 0, stream>>>(erow, ecol, eval_, counts, ep, qsum,
                                                       w3, w2, w1, Wt);
    gemm_mfma3_kernel<<<(N_NODES + 63) / 64, 256, 0, stream>>>(F, Wt, T1, N_NODES);

    const int spmmGrid = N_NODES / 8;  // 6250, exact

    // S1: A*[h3|h2|h1] -> [u3|v2](T2) + f1h (csum slot 0)
    spmm1_kernel<<<spmmGrid, 512, 0, stream>>>(counts, ep, T1, T2, f1h, csum);
    // S2: A*[u3|v2] -> [w3](T3) + f2h (csum slot 1) + csum slot2 via q^T T3
    spmm2_kernel<<<spmmGrid, 512, 0, stream>>>(counts, ep, T2, T3, f2h, qsum, csum);
    // S3 + FC/softmax + combine -> d_out
    spmm3_combine_kernel<<<spmmGrid, 512, 0, stream>>>(counts, ep, T3, f1h, f2h, csum,
                                                       b1, b2, b3, fc1w, fc1b, fc2w, fc2b, out);
}

// Round 11
// 345.618 us; speedup vs baseline: 1.1838x; 1.1838x over previous
//
#include <hip/hip_runtime.h>
#include <cstdint>

#define N_NODES 50000
#define N_EDGES 800000
#define EPCAP 64

typedef _Float16 half8 __attribute__((ext_vector_type(8)));
typedef float f32x4 __attribute__((ext_vector_type(4)));

// ---------------- f16 helpers ----------------

__device__ inline unsigned pack_half2(float lo, float hi) {
    union { _Float16 h[2]; unsigned u; } cv;
    cv.h[0] = (_Float16)lo; cv.h[1] = (_Float16)hi;
    return cv.u;
}
__device__ inline float h_lo(unsigned u) {
    union { unsigned u; _Float16 h[2]; } cv; cv.u = u; return (float)cv.h[0];
}
__device__ inline float h_hi(unsigned u) {
    union { unsigned u; _Float16 h[2]; } cv; cv.u = u; return (float)cv.h[1];
}

// ---------------- fused pre-kernel: gemm (blocks 0..781) + scatter (782..3906) ----------
// Only 32KB LDS (Ws) so scatter blocks keep >=5 blocks/CU occupancy.
// gemm: A-frags straight from global F (r6-validated); T1 chunked layout:
//   dword (row*192 + b*64 + j) = branch b, dims (j, j+64)
// scatter: ep[row*64 + slot] = (f16val << 16) | col

__global__ __launch_bounds__(256) void pre_kernel(const int* __restrict__ rows,
                                                  const int* __restrict__ cols,
                                                  const float* __restrict__ vals,
                                                  int* __restrict__ cnt,
                                                  unsigned* __restrict__ ep,
                                                  const float* __restrict__ F,
                                                  const float* __restrict__ w3,
                                                  const float* __restrict__ w2,
                                                  const float* __restrict__ w1,
                                                  unsigned* __restrict__ T1) {
    __shared__ _Float16 Ws[128 * 128];   // 32 KiB, [j][k] XOR-swizzled
    int bx = blockIdx.x;
    int tid = threadIdx.x;

    if (bx >= 782) {
        // ---- scatter: (3907-782)*256 == 800000 exactly ----
        int e = (bx - 782) * 256 + tid;
        int r = rows[e];
        int p = atomicAdd(&cnt[r], 1);
        union { _Float16 h; unsigned short s; } cv; cv.h = (_Float16)vals[e];
        if (p < EPCAP)
            __builtin_nontemporal_store(((unsigned)cv.s << 16) | (unsigned)cols[e],
                                        &ep[(size_t)r * EPCAP + p]);
        return;
    }

    // ---- gemm ----
    int lane = tid & 63, wv = tid >> 6;
    int c = lane & 15, g = lane >> 4;
    int rowbase = bx * 64;

    // A fragments straight from global f32 (row = wv*16+c, two float4 per ks)
    half8 afr[4];
    {
        int row = rowbase + wv * 16 + c;
        if (row >= N_NODES) row = N_NODES - 1;
        const float* fr = F + (size_t)row * 128;
        #pragma unroll
        for (int ks = 0; ks < 4; ++ks) {
            const float4* s4 = (const float4*)(fr + ks * 32 + g * 8);
            float4 x0 = s4[0], x1 = s4[1];
            half8 a;
            a[0] = (_Float16)x0.x; a[1] = (_Float16)x0.y;
            a[2] = (_Float16)x0.z; a[3] = (_Float16)x0.w;
            a[4] = (_Float16)x1.x; a[5] = (_Float16)x1.y;
            a[6] = (_Float16)x1.z; a[7] = (_Float16)x1.w;
            afr[ks] = a;
        }
    }

    for (int b = 0; b < 3; ++b) {
        const float* W = (b == 0) ? w3 : (b == 1) ? w2 : w1;
        // stage W f32 [d][j] -> Ws f16 [j][d], XOR swizzle ((j&15)<<4)
        for (int i = tid; i < 16384; i += 256) {
            int d = i >> 7, j = i & 127;
            *(_Float16*)((char*)Ws + (((j * 128 + d) * 2) ^ ((j & 15) << 4))) = (_Float16)W[i];
        }
        __syncthreads();

        f32x4 zero = {0.f, 0.f, 0.f, 0.f};
        f32x4 acc[8];
        #pragma unroll
        for (int t = 0; t < 8; ++t) acc[t] = zero;

        #pragma unroll
        for (int ks = 0; ks < 4; ++ks) {
            #pragma unroll
            for (int t = 0; t < 8; ++t) {
                int j = t * 16 + c;
                int off = ((j * 128 + ks * 32 + g * 8) * 2) ^ ((j & 15) << 4);
                half8 bfr = *(const half8*)((const char*)Ws + off);
                acc[t] = __builtin_amdgcn_mfma_f32_16x16x32_f16(afr[ks], bfr, acc[t], 0, 0, 0);
            }
        }

        // lane holds cols j=t*16+c (lo) and j+64 (tile t+4), rows g*4+r
        #pragma unroll
        for (int t = 0; t < 4; ++t) {
            int j = t * 16 + c;
            #pragma unroll
            for (int r = 0; r < 4; ++r) {
                int row = rowbase + wv * 16 + g * 4 + r;
                if (row < N_NODES)
                    T1[(size_t)row * 192 + b * 64 + j] =
                        pack_half2(tanhf(acc[t][r]), tanhf(acc[t + 4][r]));
            }
        }
        __syncthreads();
    }
}

// ---------------- batched SpMM stage (round-7/9 exact: 1 wave per row, 8 rows/block) ----
// x row = NCHUNK chunks of 64 dwords, lane reads dword `lane` of each chunk
// (dword g = dims g, g+64). Chunks 0..NCHUNK-2 -> ob0; final chunk -> obf (f16) and
// column-summed into csum (8-way replicated via LDS block reduce).

template <int NCHUNK>
__global__ __launch_bounds__(512) void spmm_stage_kernel(const int* __restrict__ cnts,
                                                         const unsigned* __restrict__ ep,
                                                         const unsigned* __restrict__ x,
                                                         unsigned* __restrict__ ob0,
                                                         unsigned* __restrict__ obf,
                                                         float* __restrict__ csumK) {
    __shared__ float cs[128];
    int tid = threadIdx.x;
    if (tid < 128) cs[tid] = 0.f;
    __syncthreads();

    int row = blockIdx.x * 8 + (tid >> 6);
    int lane = tid & 63;
    int n = __builtin_amdgcn_readfirstlane(cnts[row]);
    n = n < EPCAP ? n : EPCAP;
    const unsigned* e0 = ep + (size_t)row * EPCAP;

    float ax[NCHUNK], ay[NCHUNK];
    #pragma unroll
    for (int cc = 0; cc < NCHUNK; ++cc) { ax[cc] = 0.f; ay[cc] = 0.f; }

    const unsigned* xl = x + lane;
    constexpr int U = 8;
    int i = 0;
    for (; i + U <= n; i += U) {
        unsigned p[U];
        #pragma unroll
        for (int u = 0; u < U; ++u) p[u] = e0[i + u];
        unsigned gx[U][NCHUNK];
        #pragma unroll
        for (int u = 0; u < U; ++u) {
            unsigned b = (p[u] & 0xFFFFu) * (unsigned)(NCHUNK * 64);
            #pragma unroll
            for (int cc = 0; cc < NCHUNK; ++cc) gx[u][cc] = xl[b + cc * 64];
        }
        #pragma unroll
        for (int u = 0; u < U; ++u) {
            union { unsigned short s; _Float16 h; } cu; cu.s = (unsigned short)(p[u] >> 16);
            float v = (float)cu.h;
            #pragma unroll
            for (int cc = 0; cc < NCHUNK; ++cc) {
                ax[cc] += v * h_lo(gx[u][cc]);
                ay[cc] += v * h_hi(gx[u][cc]);
            }
        }
    }
    for (; i < n; ++i) {
        unsigned p = e0[i];
        unsigned b = (p & 0xFFFFu) * (unsigned)(NCHUNK * 64);
        union { unsigned short s; _Float16 h; } cu; cu.s = (unsigned short)(p >> 16);
        float v = (float)cu.h;
        #pragma unroll
        for (int cc = 0; cc < NCHUNK; ++cc) {
            unsigned gg = xl[b + cc * 64];
            ax[cc] += v * h_lo(gg);
            ay[cc] += v * h_hi(gg);
        }
    }

    #pragma unroll
    for (int cc = 0; cc < NCHUNK - 1; ++cc)
        ob0[(size_t)row * ((NCHUNK - 1) * 64) + cc * 64 + lane] = pack_half2(ax[cc], ay[cc]);

    float fx = ax[NCHUNK - 1], fy = ay[NCHUNK - 1];
    obf[(size_t)row * 64 + lane] = pack_half2(fx, fy);
    atomicAdd(&cs[2 * lane + 0], fx);   // slot 2g   <-> dim g
    atomicAdd(&cs[2 * lane + 1], fy);   // slot 2g+1 <-> dim g+64
    __syncthreads();
    if (tid < 128) atomicAdd(&csumK[(blockIdx.x & 7) * 384 + tid], cs[tid]);
}

// ---------------- combine (with fused FC+softmax): out = sum_k (fk+bk)*wgt_k ----------------
// f1/f2/f3 all dim-split f16 dwords (dword g = dims g, g+64); d_out written once, f32.

__global__ __launch_bounds__(256) void combine_kernel(float* __restrict__ out,
                                                      const unsigned* __restrict__ f1,
                                                      const unsigned* __restrict__ f2,
                                                      const unsigned* __restrict__ f3,
                                                      const float* __restrict__ csum,
                                                      const float* __restrict__ b1,
                                                      const float* __restrict__ b2,
                                                      const float* __restrict__ b3,
                                                      const float* __restrict__ fc1w,
                                                      const float* __restrict__ fc1b,
                                                      const float* __restrict__ fc2w,
                                                      const float* __restrict__ fc2b) {
    __shared__ float m[3][128];
    __shared__ float rr[3][32];
    __shared__ float wgt[3][128];
    int t = threadIdx.x;

    if (t < 128) {
        const float inv = 1.0f / (float)N_NODES;
        int slot = (t < 64) ? (2 * t) : (2 * (t - 64) + 1);
        #pragma unroll
        for (int k = 0; k < 3; ++k) {
            float s = 0.f;
            #pragma unroll
            for (int rep = 0; rep < 8; ++rep) s += csum[rep * 384 + k * 128 + slot];
            const float* bk = (k == 0) ? b1 : (k == 1) ? b2 : b3;
            m[k][t] = s * inv + bk[t];
        }
    }
    __syncthreads();
    if (t < 96) {
        int k = t >> 5, j = t & 31;
        float acc = fc1b[j];
        for (int d = 0; d < 128; ++d) acc += m[k][d] * fc1w[d * 32 + j];
        rr[k][j] = fmaxf(acc, 0.f);
    }
    __syncthreads();
    if (t < 128) {
        float a[3];
        #pragma unroll
        for (int k = 0; k < 3; ++k) {
            float acc = fc2b[t];
            for (int j = 0; j < 32; ++j) acc += rr[k][j] * fc2w[j * 128 + t];
            a[k] = acc;
        }
        float mx = fmaxf(a[0], fmaxf(a[1], a[2]));
        float e0 = expf(a[0] - mx), e1 = expf(a[1] - mx), e2 = expf(a[2] - mx);
        float s = e0 + e1 + e2;
        wgt[0][t] = e0 / s;
        wgt[1][t] = e1 / s;
        wgt[2][t] = e2 / s;
    }
    __syncthreads();

    const int total = N_NODES * 32;  // float4 count
    int idx0 = blockIdx.x * blockDim.x + threadIdx.x;
    int stride = gridDim.x * blockDim.x;  // multiple of 32
    int qb = idx0 & 31;                   // float4 slot in row: dims 4qb..4qb+3
    float4 W0 = *(const float4*)&wgt[0][qb * 4];
    float4 W1 = *(const float4*)&wgt[1][qb * 4];
    float4 W2 = *(const float4*)&wgt[2][qb * 4];
    float4 B1 = ((const float4*)b1)[qb];
    float4 B2 = ((const float4*)b2)[qb];
    float4 B3 = ((const float4*)b3)[qb];
    bool hi = qb >= 16;
    int qm = qb & 15;
    for (int idx = idx0; idx < total; idx += stride) {
        int row = idx >> 5;
        uint4 u1 = ((const uint4*)f1)[row * 16 + qm];
        uint4 u2 = ((const uint4*)f2)[row * 16 + qm];
        uint4 u3 = ((const uint4*)f3)[row * 16 + qm];
        float f1x = hi ? h_hi(u1.x) : h_lo(u1.x);
        float f1y = hi ? h_hi(u1.y) : h_lo(u1.y);
        float f1z = hi ? h_hi(u1.z) : h_lo(u1.z);
        float f1w = hi ? h_hi(u1.w) : h_lo(u1.w);
        float f2x = hi ? h_hi(u2.x) : h_lo(u2.x);
        float f2y = hi ? h_hi(u2.y) : h_lo(u2.y);
        float f2z = hi ? h_hi(u2.z) : h_lo(u2.z);
        float f2w = hi ? h_hi(u2.w) : h_lo(u2.w);
        float f3x = hi ? h_hi(u3.x) : h_lo(u3.x);
        float f3y = hi ? h_hi(u3.y) : h_lo(u3.y);
        float f3z = hi ? h_hi(u3.z) : h_lo(u3.z);
        float f3w = hi ? h_hi(u3.w) : h_lo(u3.w);
        float4 o;
        o.x = (f1x + B1.x) * W0.x + (f2x + B2.x) * W1.x + (f3x + B3.x) * W2.x;
        o.y = (f1y + B1.y) * W0.y + (f2y + B2.y) * W1.y + (f3y + B3.y) * W2.y;
        o.z = (f1z + B1.z) * W0.z + (f2z + B2.z) * W1.z + (f3z + B3.z) * W2.z;
        o.w = (f1w + B1.w) * W0.w + (f2w + B2.w) * W1.w + (f3w + B3.w) * W2.w;
        ((float4*)out)[idx] = o;
    }
}

// ---------------- launch ----------------

extern "C" void kernel_launch(void* const* d_in, const int* in_sizes, int n_in,
                              void* d_out, int out_size, void* d_ws, size_t ws_size,
                              hipStream_t stream) {
    const float* F    = (const float*)d_in[0];
    const int*   erow = (const int*)d_in[1];
    const int*   ecol = (const int*)d_in[2];
    const float* eval_ = (const float*)d_in[3];
    const float* w1 = (const float*)d_in[4];  const float* b1 = (const float*)d_in[5];
    const float* w2 = (const float*)d_in[6];  const float* b2 = (const float*)d_in[7];
    const float* w3 = (const float*)d_in[8];  const float* b3 = (const float*)d_in[9];
    const float* fc1w = (const float*)d_in[10]; const float* fc1b = (const float*)d_in[11];
    const float* fc2w = (const float*)d_in[12]; const float* fc2b = (const float*)d_in[13];
    float* out = (float*)d_out;

    char* ws = (char*)d_ws;
    size_t off = 0;
    auto alloc = [&](size_t bytes) -> void* {
        off = (off + 255) & ~(size_t)255;
        void* p = ws + off;
        off += bytes;
        return p;
    };
    unsigned* T1   = (unsigned*)alloc((size_t)N_NODES * 192 * 4);       // 38.4 MB [h3|h2|h1]
    unsigned* T2   = (unsigned*)alloc((size_t)N_NODES * 128 * 4);       // 25.6 MB [u3|v2]
    unsigned* T3   = (unsigned*)alloc((size_t)N_NODES * 64 * 4);        // 12.8 MB [w3]
    unsigned* f1h  = (unsigned*)alloc((size_t)N_NODES * 64 * 4);        // 12.8 MB f1 (f16)
    unsigned* ep   = (unsigned*)alloc((size_t)N_NODES * EPCAP * 4);     // 12.8 MB edge buckets
    int*   counts  = (int*)alloc((size_t)N_NODES * sizeof(int));
    float* csum    = (float*)alloc(8 * 3 * 128 * sizeof(float));        // adjacent to counts
    unsigned* f2h  = T1;                               // alias: T1 dead after S1
    unsigned* f3h  = T1 + (size_t)N_NODES * 64;

    // one memset covers counts + pad + csum (allocated adjacently)
    size_t zlen = (size_t)((char*)csum + 8 * 3 * 128 * sizeof(float) - (char*)counts);
    hipMemsetAsync(counts, 0, zlen, stream);

    // fused gemm (782 blocks, 32KB LDS only) + scatter (3125 blocks)
    pre_kernel<<<782 + 3125, 256, 0, stream>>>(erow, ecol, eval_, counts, ep,
                                               F, w3, w2, w1, T1);

    const int spmmGrid = N_NODES / 8;  // 6250, exact

    // S1: A*[h3|h2|h1] -> [u3|v2](T2) + f1h (csum slot 0)
    spmm_stage_kernel<3><<<spmmGrid, 512, 0, stream>>>(counts, ep, T1, T2, f1h, csum + 0 * 128);
    // S2: A*[u3|v2] -> [w3](T3) + f2h (csum slot 1)
    spmm_stage_kernel<2><<<spmmGrid, 512, 0, stream>>>(counts, ep, T2, T3, f2h, csum + 1 * 128);
    // S3: A*[w3] -> f3h (csum slot 2)
    spmm_stage_kernel<1><<<spmmGrid, 512, 0, stream>>>(counts, ep, T3, nullptr, f3h, csum + 2 * 128);

    combine_kernel<<<2048, 256, 0, stream>>>(out, f1h, f2h, f3h, csum, b1, b2, b3,
                                             fc1w, fc1b, fc2w, fc2b);
}